// Round 10
// baseline (300.521 us; speedup 1.0000x reference)
//
#include <hip/hip_runtime.h>
#include <math.h>

// S4D — round 16: LTI/chunked-convolution reformulation onto the MFMA pipe.
// state0 = 0 and the system is linear time-invariant, so per (b,h,chunk c):
//   y_c   = T_h @ x_c + M_h @ u_in(c) + D*x  (then gelu)
//   P_c   = V_h @ x_c
//   u_in(c+1) = Lambda_h (.) u_in(c) + P_c       (diagonal, 64 seq steps only)
// with T_h[t][s] = k[t-s] (tril, k_d = Re(w dA^d dB), w = 2C),
//      M_h[t][2n,2n+1] = (Re, -Im)(w_n dA_n^{t+1}),
//      V_h[2n,2n+1][s] = (Re, Im)(dA_n^{63-s} dB_n),  Lambda = dA^64.
// All three 64x64 matmuls batch 256 columns (4 b x 64 c) per block via
// v_mfma_f32_16x16x32_f16 (f32 accumulation). A/B frags both read 8
// contiguous k at row/col = lane&15, kgroup = lane>>4 from row-major
// storage: any true HW k-permutation applied equally to A and B leaves
// A@B invariant; C/D mapping (col=lane&15, row=(lane>>4)*4+reg) is the
// HW-verified one. x gathered per-h as f16 (r15 proved the precision).
// Grid: 1024 blocks = 512 h x 2 b-halves, 256 thr (4 waves = 4 batches),
// 75 KB LDS -> 2 blocks/CU. XCD swizzle keeps h-neighbors on one XCD so
// the stride-H gather/scatter 64B lines are L2-shared by 16 h-blocks.

#define H_  512
#define L_  4096
#define B_  8
#define N2_ 32
#define NC  64            // chunks of 64 timesteps
#define THREADS 256
#define BW  4             // batches (waves) per block
#define COLS 256          // columns per block = BW*64
#define RSTR 72           // padded LDS row stride, f16 units (144B, 16B-mult)

typedef _Float16 f16;
typedef _Float16 f16x8 __attribute__((ext_vector_type(8)));
typedef _Float16 f16x4 __attribute__((ext_vector_type(4)));
typedef float    f32x4 __attribute__((ext_vector_type(4)));

__device__ __forceinline__ float bfly1(float v) {   // xor 1: quad_perm [1,0,3,2]
    return __int_as_float(__builtin_amdgcn_update_dpp(
        0, __float_as_int(v), 0xB1, 0xf, 0xf, true));
}

__global__ __launch_bounds__(THREADS, 2) void s4d_conv_kernel(
    const float* __restrict__ x,          // (B, L, H)
    const float* __restrict__ log_dt,     // (H,)
    const float* __restrict__ A_real_log, // (H, N2)
    const float* __restrict__ A_imag,     // (H, N2)
    const float* __restrict__ B_re,       // (H, N2)
    const float* __restrict__ B_im,       // (H, N2)
    const float* __restrict__ C_re,       // (H, N2)
    const float* __restrict__ C_im,       // (H, N2)
    const float* __restrict__ Dv,         // (H,)
    float* __restrict__ out_y,            // (B, L, H)
    float* __restrict__ st_re,            // (B, H, N2)
    float* __restrict__ st_im)            // (B, H, N2)
{
    // Xl: phase 1-2 holds T (rows 0..63), M (64..127), V (128..191) f16;
    //     phase 4+ holds X tile [col][s].
    // PU: phase 1-2 holds dApow table (f32); phase 5+ holds P then U [col][j].
    __shared__ f16 Xl[COLS][RSTR];                 // 36.9 KB
    __shared__ f16 PU[COLS][RSTR];                 // 36.9 KB
    __shared__ float s_xr[32], s_xi[32], s_dBr[32], s_dBi[32],
                     s_wr[32], s_wi[32], s_wdr[32], s_wdi[32],
                     s_Lr[32], s_Li[32], s_k[64];

    // XCD swizzle: XCD k owns h in [k*64, (k+1)*64), both b-halves.
    const int bid = (int)blockIdx.x;
    const int li  = bid >> 3;                       // 0..127
    const int h   = (bid & 7) * 64 + (li >> 1);
    const int bh  = li & 1;                         // batch half (b = bh*4+w)

    const int tid = threadIdx.x;
    const int l   = tid & 63;
    const int w   = tid >> 6;                       // wave = local batch

    // ---- P0: per-mode ZOH constants (32 threads) ----
    if (tid < 32) {
        const int n = tid, hn = h * N2_ + n;
        const float dt = expf(log_dt[h]);
        const float Ar = -expf(A_real_log[hn]);
        const float Ai = A_imag[hn];
        const float xr = dt * Ar, xi = dt * Ai;
        s_xr[n] = xr; s_xi[n] = xi;
        const float ex = expf(xr), cs = cosf(xi), sn = sinf(xi);
        const float sh  = sinf(0.5f * xi);
        const float emr = expm1f(xr) * cs - 2.0f * sh * sh;  // Re(expm1(dtA))
        const float emi = ex * sn;
        const float ia  = 1.0f / (Ar * Ar + Ai * Ai);
        const float tr  = (emr * Ar + emi * Ai) * ia;
        const float ti  = (emi * Ar - emr * Ai) * ia;
        const float Brv = B_re[hn], Biv = B_im[hn];
        const float dBr = Brv * tr - Biv * ti, dBi = Brv * ti + Biv * tr;
        s_dBr[n] = dBr; s_dBi[n] = dBi;
        const float wr = 2.0f * C_re[hn], wi = 2.0f * C_im[hn];
        s_wr[n] = wr; s_wi[n] = wi;
        s_wdr[n] = wr * dBr - wi * dBi;             // w*dB
        s_wdi[n] = wr * dBi + wi * dBr;
    }
    const float Dh = Dv[h];
    __syncthreads();

    // ---- P1: dApow[p][n] = dA_n^p, p = 0..64, in PU area (f32) ----
    float* pr = (float*)&PU[0][0];                  // [65*32]
    float* pi = pr + 65 * 32;
    for (int e = tid; e < 65 * 32; e += THREADS) {
        const int p = e >> 5, n = e & 31;
        const float ex = expf((float)p * s_xr[n]);
        float sn, cs; sincosf((float)p * s_xi[n], &sn, &cs);
        pr[e] = ex * cs; pi[e] = ex * sn;
    }
    __syncthreads();

    // ---- P2: build k, Lambda, M, V (then T after barrier) ----
    if (tid < 64) {                                 // k[d] = Re(w dB dA^d)
        float acc = 0.f;
        for (int n = 0; n < 32; ++n)
            acc += s_wdr[n] * pr[tid * 32 + n] - s_wdi[n] * pi[tid * 32 + n];
        s_k[tid] = acc;
    }
    if (tid < 32) { s_Lr[tid] = pr[64 * 32 + tid]; s_Li[tid] = pi[64 * 32 + tid]; }
    for (int e = tid; e < 4096; e += THREADS) {     // M[t][j], rows 64..127
        const int t = e >> 6, j = e & 63, n = j >> 1;
        const float re = pr[(t + 1) * 32 + n], im = pi[(t + 1) * 32 + n];
        const float mv = (j & 1) ? -(s_wr[n] * im + s_wi[n] * re)
                                 :  (s_wr[n] * re - s_wi[n] * im);
        Xl[64 + t][j] = (f16)mv;
    }
    for (int e = tid; e < 4096; e += THREADS) {     // V[r][s], rows 128..191
        const int r = e >> 6, s = e & 63, n = r >> 1;
        const float re = pr[(63 - s) * 32 + n], im = pi[(63 - s) * 32 + n];
        const float vv = (r & 1) ? (s_dBr[n] * im + s_dBi[n] * re)
                                 : (s_dBr[n] * re - s_dBi[n] * im);
        Xl[128 + r][s] = (f16)vv;
    }
    __syncthreads();
    for (int e = tid; e < 4096; e += THREADS) {     // T[t][s], rows 0..63
        const int t = e >> 6, s = e & 63;
        Xl[t][s] = (f16)((s <= t) ? s_k[t - s] : 0.f);
    }
    __syncthreads();

    // ---- P3: A-fragments to registers (row = l&15, kgroup = l>>4) ----
    const int row16 = l & 15, kg = l >> 4;
    f16x8 Tf[4][2], Mf[4][2], Vf[4][2];
#pragma unroll
    for (int mt = 0; mt < 4; ++mt)
#pragma unroll
        for (int ks = 0; ks < 2; ++ks) {
            const int off = ks * 32 + kg * 8;
            Tf[mt][ks] = *(const f16x8*)&Xl[      mt * 16 + row16][off];
            Mf[mt][ks] = *(const f16x8*)&Xl[ 64 + mt * 16 + row16][off];
            Vf[mt][ks] = *(const f16x8*)&Xl[128 + mt * 16 + row16][off];
        }
    __syncthreads();   // frags live in regs; Xl area free for X

    // ---- P4: gather X (thread = column; stride-H scatter, L2-shared) ----
    {
        const int col = tid, b = bh * 4 + (col >> 6), c = col & 63;
        const float* xg = x + ((size_t)b * L_ + (size_t)c * 64) * H_ + h;
        for (int s0 = 0; s0 < 64; s0 += 8) {
            float v[8];
#pragma unroll
            for (int j = 0; j < 8; ++j) v[j] = xg[(size_t)(s0 + j) * H_];
            f16x8 pk;
#pragma unroll
            for (int j = 0; j < 8; ++j) pk[j] = (f16)v[j];
            *(f16x8*)&Xl[col][s0] = pk;
        }
    }
    __syncthreads();

    const int colbase = w * 64;

    // ---- P5: P = V @ X for this wave's 64 columns ----
#pragma unroll 1
    for (int nt = 0; nt < 4; ++nt) {
        const int col = colbase + nt * 16 + row16;
        const f16x8 xb0 = *(const f16x8*)&Xl[col][kg * 8];
        const f16x8 xb1 = *(const f16x8*)&Xl[col][32 + kg * 8];
        f32x4 ac0 = {0.f,0.f,0.f,0.f}, ac1 = {0.f,0.f,0.f,0.f},
              ac2 = {0.f,0.f,0.f,0.f}, ac3 = {0.f,0.f,0.f,0.f};
        ac0 = __builtin_amdgcn_mfma_f32_16x16x32_f16(Vf[0][0], xb0, ac0, 0,0,0);
        ac0 = __builtin_amdgcn_mfma_f32_16x16x32_f16(Vf[0][1], xb1, ac0, 0,0,0);
        ac1 = __builtin_amdgcn_mfma_f32_16x16x32_f16(Vf[1][0], xb0, ac1, 0,0,0);
        ac1 = __builtin_amdgcn_mfma_f32_16x16x32_f16(Vf[1][1], xb1, ac1, 0,0,0);
        ac2 = __builtin_amdgcn_mfma_f32_16x16x32_f16(Vf[2][0], xb0, ac2, 0,0,0);
        ac2 = __builtin_amdgcn_mfma_f32_16x16x32_f16(Vf[2][1], xb1, ac2, 0,0,0);
        ac3 = __builtin_amdgcn_mfma_f32_16x16x32_f16(Vf[3][0], xb0, ac3, 0,0,0);
        ac3 = __builtin_amdgcn_mfma_f32_16x16x32_f16(Vf[3][1], xb1, ac3, 0,0,0);
        f32x4 a4[4] = {ac0, ac1, ac2, ac3};
#pragma unroll
        for (int mt = 0; mt < 4; ++mt) {
            f16x4 pv;
            pv[0] = (f16)a4[mt][0]; pv[1] = (f16)a4[mt][1];
            pv[2] = (f16)a4[mt][2]; pv[3] = (f16)a4[mt][3];
            *(f16x4*)&PU[col][mt * 16 + kg * 4] = pv;   // row j, col
        }
    }

    // ---- P6: wave-local diagonal recurrence over chunks (b = bh*4+w) ----
    {
        const int j = l, n = j >> 1;
        const float lr  = s_Lr[n];
        const float lis = (j & 1) ? s_Li[n] : -s_Li[n];
        float u = 0.f;
        for (int c = 0; c < NC; ++c) {
            const int col = colbase + c;
            const float pv = (float)PU[col][j];     // P_c component
            PU[col][j] = (f16)u;                    // store u_in(c) pre-update
            const float usw = bfly1(u);
            u = fmaf(lr, u, fmaf(lis, usw, pv));
        }
        const int pairIdx = (bh * 4 + w) * H_ + h;
        if ((j & 1) == 0) st_re[(size_t)pairIdx * N2_ + n] = u;
        else              st_im[(size_t)pairIdx * N2_ + n] = u;
    }

    // ---- P7: Y = T @ X + M @ U + D*x, gelu, scatter-store ----
    {
        const int b = bh * 4 + w;
        float* yb = out_y + (size_t)b * L_ * H_ + h;
#pragma unroll 1
        for (int nt = 0; nt < 4; ++nt) {
            const int col = colbase + nt * 16 + row16;
            const int cc  = nt * 16 + row16;        // chunk index
            const f16x8 xb0 = *(const f16x8*)&Xl[col][kg * 8];
            const f16x8 xb1 = *(const f16x8*)&Xl[col][32 + kg * 8];
            const f16x8 ub0 = *(const f16x8*)&PU[col][kg * 8];
            const f16x8 ub1 = *(const f16x8*)&PU[col][32 + kg * 8];
#pragma unroll
            for (int mt = 0; mt < 4; ++mt) {
                f32x4 ac = {0.f, 0.f, 0.f, 0.f};
                ac = __builtin_amdgcn_mfma_f32_16x16x32_f16(Tf[mt][0], xb0, ac, 0,0,0);
                ac = __builtin_amdgcn_mfma_f32_16x16x32_f16(Tf[mt][1], xb1, ac, 0,0,0);
                ac = __builtin_amdgcn_mfma_f32_16x16x32_f16(Mf[mt][0], ub0, ac, 0,0,0);
                ac = __builtin_amdgcn_mfma_f32_16x16x32_f16(Mf[mt][1], ub1, ac, 0,0,0);
                const int t0 = mt * 16 + kg * 4;
                const f16x4 xs = *(const f16x4*)&Xl[col][t0];
                float* yp = yb + ((size_t)cc * 64 + t0) * H_;
#pragma unroll
                for (int r = 0; r < 4; ++r) {
                    const float y  = fmaf(Dh, (float)xs[r], ac[r]);
                    const float y2 = y * y;
                    const float arg = y * fmaf(-0.10294502f, y2, -2.30218425f);
                    const float e   = __builtin_amdgcn_exp2f(arg);
                    const float gy  = y * __builtin_amdgcn_rcpf(1.0f + e);
                    yp[(size_t)r * H_] = gy;
                }
            }
        }
    }
}

extern "C" void kernel_launch(void* const* d_in, const int* in_sizes, int n_in,
                              void* d_out, int out_size, void* d_ws, size_t ws_size,
                              hipStream_t stream) {
    (void)in_sizes; (void)n_in; (void)d_ws; (void)ws_size; (void)out_size;
    const float* x    = (const float*)d_in[0];
    const float* ldt  = (const float*)d_in[1];
    const float* Arl  = (const float*)d_in[2];
    const float* Aim  = (const float*)d_in[3];
    const float* Bre  = (const float*)d_in[4];
    const float* Bim  = (const float*)d_in[5];
    const float* Cre  = (const float*)d_in[6];
    const float* Cim  = (const float*)d_in[7];
    const float* Dv   = (const float*)d_in[8];
    float* out = (float*)d_out;
    float* st_re = out + (size_t)B_ * L_ * H_;       // ys first
    float* st_im = st_re + (size_t)B_ * H_ * N2_;    // then imag plane

    dim3 grid(1024);            // 512 h x 2 batch-halves; 2 blocks/CU
    dim3 block(THREADS);        // 256 thr = 4 waves = 4 batches
    hipLaunchKernelGGL(s4d_conv_kernel, grid, block, 0, stream,
                       x, ldt, Arl, Aim, Bre, Bim, Cre, Cim, Dv, out, st_re, st_im);
}

// Round 11
// 187.412 us; speedup vs baseline: 1.6035x; 1.6035x over previous
//
#include <hip/hip_runtime.h>
#include <math.h>

// S4D — round 17: r16's verified MFMA conv kernel + coalescing transposes.
//   A: x (B,L,H) f32 -> xT (H,B,L) f16   (xT lives in out's y region, which
//      is only written later by C and never read as xT after B)
//   B: r16 conv (per-h T/M/V matmuls + diagonal chunk recurrence), but
//      gather = contiguous f16x8 reads from xT, store = contiguous f16x4
//      writes to yT (workspace, 32 MiB). Math identical to r16 (verified).
//   C: yT (H,B,L) f16 -> y (B,L,H) f32 (gelu already applied in B).
// r16's 212us had MfmaUtil 1.2%/VALUBusy 7.5%: pure access-pattern cost
// (1 h per block -> 64 lines per wave memory op). This fixes the layout.

#define H_  512
#define L_  4096
#define B_  8
#define N2_ 32
#define NC  64            // chunks of 64 timesteps
#define THREADS 256
#define COLS 256          // columns per conv block = 4 b x 64 c
#define RSTR 72           // padded LDS row stride, f16 units

typedef _Float16 f16;
typedef _Float16 f16x8 __attribute__((ext_vector_type(8)));
typedef _Float16 f16x4 __attribute__((ext_vector_type(4)));
typedef float    f32x4 __attribute__((ext_vector_type(4)));

__device__ __forceinline__ float bfly1(float v) {   // xor 1: quad_perm [1,0,3,2]
    return __int_as_float(__builtin_amdgcn_update_dpp(
        0, __float_as_int(v), 0xB1, 0xf, 0xf, true));
}

// ---------------- kernel A: x (B,L,H) f32 -> xT (H,B,L) f16 ----------------
__global__ __launch_bounds__(256) void k_trin(
    const float* __restrict__ x, f16* __restrict__ xT)
{
    __shared__ float tl[64][65];
    const int bid = (int)blockIdx.x;
    const int tt = bid & 63, hh = (bid >> 6) & 7, b = bid >> 9;
    const int t0 = tt * 64, h0 = hh * 64;
    const int lane = threadIdx.x & 63, r = threadIdx.x >> 6;

    const float* src = x + ((size_t)b * L_ + t0) * H_ + h0;
#pragma unroll
    for (int p = 0; p < 16; ++p) {
        const int t = p * 4 + r;
        tl[t][lane] = src[(size_t)t * H_ + lane];
    }
    __syncthreads();
#pragma unroll
    for (int p = 0; p < 16; ++p) {
        const int hI = p * 4 + r;
        f16* dst = xT + ((size_t)(h0 + hI) * B_ + b) * L_ + t0;
        dst[lane] = (f16)tl[lane][hI];
    }
}

// ---------------- kernel C: yT (H,B,L) f16 -> y (B,L,H) f32 ----------------
__global__ __launch_bounds__(256) void k_trout(
    const f16* __restrict__ yT, float* __restrict__ y)
{
    __shared__ float tl[64][65];
    const int bid = (int)blockIdx.x;
    const int tt = bid & 63, hh = (bid >> 6) & 7, b = bid >> 9;
    const int t0 = tt * 64, h0 = hh * 64;
    const int lane = threadIdx.x & 63, r = threadIdx.x >> 6;

#pragma unroll
    for (int p = 0; p < 16; ++p) {
        const int hI = p * 4 + r;
        const f16* srow = yT + ((size_t)(h0 + hI) * B_ + b) * L_ + t0;
        tl[hI][lane] = (float)srow[lane];
    }
    __syncthreads();
#pragma unroll
    for (int p = 0; p < 16; ++p) {
        const int tI = p * 4 + r;
        y[((size_t)b * L_ + t0 + tI) * H_ + h0 + lane] = tl[lane][tI];
    }
}

// ---------------- kernel B: per-h chunked convolution (r16 core) ----------
__global__ __launch_bounds__(THREADS, 2) void s4d_conv_kernel(
    const f16*  __restrict__ xT,          // (H, B, L) f16
    const float* __restrict__ log_dt,     // (H,)
    const float* __restrict__ A_real_log, // (H, N2)
    const float* __restrict__ A_imag,     // (H, N2)
    const float* __restrict__ B_re,       // (H, N2)
    const float* __restrict__ B_im,       // (H, N2)
    const float* __restrict__ C_re,       // (H, N2)
    const float* __restrict__ C_im,       // (H, N2)
    const float* __restrict__ Dv,         // (H,)
    f16*  __restrict__ yT,                // (H, B, L) f16 (gelu'd)
    float* __restrict__ st_re,            // (B, H, N2)
    float* __restrict__ st_im)            // (B, H, N2)
{
    __shared__ f16 Xl[COLS][RSTR];                 // 36.9 KB
    __shared__ f16 PU[COLS][RSTR];                 // 36.9 KB
    __shared__ float s_xr[32], s_xi[32], s_dBr[32], s_dBi[32],
                     s_wr[32], s_wi[32], s_wdr[32], s_wdi[32],
                     s_Lr[32], s_Li[32], s_k[64];

    // XCD swizzle: XCD k owns h in [k*64, (k+1)*64), both b-halves.
    const int bid = (int)blockIdx.x;
    const int li  = bid >> 3;                       // 0..127
    const int h   = (bid & 7) * 64 + (li >> 1);
    const int bh  = li & 1;                         // batch half (b = bh*4+w)

    const int tid = threadIdx.x;
    const int l   = tid & 63;
    const int w   = tid >> 6;                       // wave = local batch

    // ---- P0: per-mode ZOH constants (32 threads) ----
    if (tid < 32) {
        const int n = tid, hn = h * N2_ + n;
        const float dt = expf(log_dt[h]);
        const float Ar = -expf(A_real_log[hn]);
        const float Ai = A_imag[hn];
        const float xr = dt * Ar, xi = dt * Ai;
        s_xr[n] = xr; s_xi[n] = xi;
        const float ex = expf(xr), cs = cosf(xi), sn = sinf(xi);
        const float sh  = sinf(0.5f * xi);
        const float emr = expm1f(xr) * cs - 2.0f * sh * sh;  // Re(expm1(dtA))
        const float emi = ex * sn;
        const float ia  = 1.0f / (Ar * Ar + Ai * Ai);
        const float tr  = (emr * Ar + emi * Ai) * ia;
        const float ti  = (emi * Ar - emr * Ai) * ia;
        const float Brv = B_re[hn], Biv = B_im[hn];
        const float dBr = Brv * tr - Biv * ti, dBi = Brv * ti + Biv * tr;
        s_dBr[n] = dBr; s_dBi[n] = dBi;
        const float wr = 2.0f * C_re[hn], wi = 2.0f * C_im[hn];
        s_wr[n] = wr; s_wi[n] = wi;
        s_wdr[n] = wr * dBr - wi * dBi;             // w*dB
        s_wdi[n] = wr * dBi + wi * dBr;
    }
    const float Dh = Dv[h];
    __syncthreads();

    // ---- P1: dApow[p][n] = dA_n^p, p = 0..64, in PU area (f32) ----
    float* pr = (float*)&PU[0][0];                  // [65*32]
    float* pi = pr + 65 * 32;
    for (int e = tid; e < 65 * 32; e += THREADS) {
        const int p = e >> 5, n = e & 31;
        const float ex = expf((float)p * s_xr[n]);
        float sn, cs; sincosf((float)p * s_xi[n], &sn, &cs);
        pr[e] = ex * cs; pi[e] = ex * sn;
    }
    __syncthreads();

    // ---- P2: build k, Lambda, M, V (then T after barrier) ----
    if (tid < 64) {                                 // k[d] = Re(w dB dA^d)
        float acc = 0.f;
        for (int n = 0; n < 32; ++n)
            acc += s_wdr[n] * pr[tid * 32 + n] - s_wdi[n] * pi[tid * 32 + n];
        s_k[tid] = acc;
    }
    if (tid < 32) { s_Lr[tid] = pr[64 * 32 + tid]; s_Li[tid] = pi[64 * 32 + tid]; }
    for (int e = tid; e < 4096; e += THREADS) {     // M[t][j], rows 64..127
        const int t = e >> 6, j = e & 63, n = j >> 1;
        const float re = pr[(t + 1) * 32 + n], im = pi[(t + 1) * 32 + n];
        const float mv = (j & 1) ? -(s_wr[n] * im + s_wi[n] * re)
                                 :  (s_wr[n] * re - s_wi[n] * im);
        Xl[64 + t][j] = (f16)mv;
    }
    for (int e = tid; e < 4096; e += THREADS) {     // V[r][s], rows 128..191
        const int r = e >> 6, s = e & 63, n = r >> 1;
        const float re = pr[(63 - s) * 32 + n], im = pi[(63 - s) * 32 + n];
        const float vv = (r & 1) ? (s_dBr[n] * im + s_dBi[n] * re)
                                 : (s_dBr[n] * re - s_dBi[n] * im);
        Xl[128 + r][s] = (f16)vv;
    }
    __syncthreads();
    for (int e = tid; e < 4096; e += THREADS) {     // T[t][s], rows 0..63
        const int t = e >> 6, s = e & 63;
        Xl[t][s] = (f16)((s <= t) ? s_k[t - s] : 0.f);
    }
    __syncthreads();

    // ---- P3: A-fragments to registers (row = l&15, kgroup = l>>4) ----
    const int row16 = l & 15, kg = l >> 4;
    f16x8 Tf[4][2], Mf[4][2], Vf[4][2];
#pragma unroll
    for (int mt = 0; mt < 4; ++mt)
#pragma unroll
        for (int ks = 0; ks < 2; ++ks) {
            const int off = ks * 32 + kg * 8;
            Tf[mt][ks] = *(const f16x8*)&Xl[      mt * 16 + row16][off];
            Mf[mt][ks] = *(const f16x8*)&Xl[ 64 + mt * 16 + row16][off];
            Vf[mt][ks] = *(const f16x8*)&Xl[128 + mt * 16 + row16][off];
        }
    __syncthreads();   // frags live in regs; Xl area free for X

    // ---- P4: load X — CONTIGUOUS f16 reads from xT (thread = column) ----
    {
        const int col = tid, b = bh * 4 + (col >> 6), c = col & 63;
        const f16* xg = xT + ((size_t)h * B_ + b) * L_ + (size_t)c * 64;
#pragma unroll
        for (int s0 = 0; s0 < 64; s0 += 8)
            *(f16x8*)&Xl[col][s0] = *(const f16x8*)&xg[s0];
    }
    __syncthreads();

    const int colbase = w * 64;

    // ---- P5: P = V @ X for this wave's 64 columns ----
#pragma unroll 1
    for (int nt = 0; nt < 4; ++nt) {
        const int col = colbase + nt * 16 + row16;
        const f16x8 xb0 = *(const f16x8*)&Xl[col][kg * 8];
        const f16x8 xb1 = *(const f16x8*)&Xl[col][32 + kg * 8];
        f32x4 ac0 = {0.f,0.f,0.f,0.f}, ac1 = {0.f,0.f,0.f,0.f},
              ac2 = {0.f,0.f,0.f,0.f}, ac3 = {0.f,0.f,0.f,0.f};
        ac0 = __builtin_amdgcn_mfma_f32_16x16x32_f16(Vf[0][0], xb0, ac0, 0,0,0);
        ac0 = __builtin_amdgcn_mfma_f32_16x16x32_f16(Vf[0][1], xb1, ac0, 0,0,0);
        ac1 = __builtin_amdgcn_mfma_f32_16x16x32_f16(Vf[1][0], xb0, ac1, 0,0,0);
        ac1 = __builtin_amdgcn_mfma_f32_16x16x32_f16(Vf[1][1], xb1, ac1, 0,0,0);
        ac2 = __builtin_amdgcn_mfma_f32_16x16x32_f16(Vf[2][0], xb0, ac2, 0,0,0);
        ac2 = __builtin_amdgcn_mfma_f32_16x16x32_f16(Vf[2][1], xb1, ac2, 0,0,0);
        ac3 = __builtin_amdgcn_mfma_f32_16x16x32_f16(Vf[3][0], xb0, ac3, 0,0,0);
        ac3 = __builtin_amdgcn_mfma_f32_16x16x32_f16(Vf[3][1], xb1, ac3, 0,0,0);
        f32x4 a4[4] = {ac0, ac1, ac2, ac3};
#pragma unroll
        for (int mt = 0; mt < 4; ++mt) {
            f16x4 pv;
            pv[0] = (f16)a4[mt][0]; pv[1] = (f16)a4[mt][1];
            pv[2] = (f16)a4[mt][2]; pv[3] = (f16)a4[mt][3];
            *(f16x4*)&PU[col][mt * 16 + kg * 4] = pv;   // row j, col
        }
    }

    // ---- P6: wave-local diagonal recurrence over chunks (b = bh*4+w) ----
    {
        const int j = l, n = j >> 1;
        const float lr  = s_Lr[n];
        const float lis = (j & 1) ? s_Li[n] : -s_Li[n];
        float u = 0.f;
        for (int c = 0; c < NC; ++c) {
            const int col = colbase + c;
            const float pv = (float)PU[col][j];     // P_c component
            PU[col][j] = (f16)u;                    // store u_in(c) pre-update
            const float usw = bfly1(u);
            u = fmaf(lr, u, fmaf(lis, usw, pv));
        }
        const int pairIdx = (bh * 4 + w) * H_ + h;
        if ((j & 1) == 0) st_re[(size_t)pairIdx * N2_ + n] = u;
        else              st_im[(size_t)pairIdx * N2_ + n] = u;
    }

    // ---- P7: Y = T @ X + M @ U + D*x, gelu, CONTIGUOUS f16 store to yT ----
    {
        const int b = bh * 4 + w;
        f16* yb = yT + ((size_t)h * B_ + b) * L_;
#pragma unroll 1
        for (int nt = 0; nt < 4; ++nt) {
            const int col = colbase + nt * 16 + row16;
            const int cc  = nt * 16 + row16;        // chunk index
            const f16x8 xb0 = *(const f16x8*)&Xl[col][kg * 8];
            const f16x8 xb1 = *(const f16x8*)&Xl[col][32 + kg * 8];
            const f16x8 ub0 = *(const f16x8*)&PU[col][kg * 8];
            const f16x8 ub1 = *(const f16x8*)&PU[col][32 + kg * 8];
#pragma unroll
            for (int mt = 0; mt < 4; ++mt) {
                f32x4 ac = {0.f, 0.f, 0.f, 0.f};
                ac = __builtin_amdgcn_mfma_f32_16x16x32_f16(Tf[mt][0], xb0, ac, 0,0,0);
                ac = __builtin_amdgcn_mfma_f32_16x16x32_f16(Tf[mt][1], xb1, ac, 0,0,0);
                ac = __builtin_amdgcn_mfma_f32_16x16x32_f16(Mf[mt][0], ub0, ac, 0,0,0);
                ac = __builtin_amdgcn_mfma_f32_16x16x32_f16(Mf[mt][1], ub1, ac, 0,0,0);
                const int t0 = mt * 16 + kg * 4;
                const f16x4 xs = *(const f16x4*)&Xl[col][t0];
                f16x4 pk;
#pragma unroll
                for (int r = 0; r < 4; ++r) {
                    const float y  = fmaf(Dh, (float)xs[r], ac[r]);
                    const float y2 = y * y;
                    const float arg = y * fmaf(-0.10294502f, y2, -2.30218425f);
                    const float e   = __builtin_amdgcn_exp2f(arg);
                    pk[r] = (f16)(y * __builtin_amdgcn_rcpf(1.0f + e));
                }
                *(f16x4*)&yb[(size_t)cc * 64 + t0] = pk;
            }
        }
    }
}

extern "C" void kernel_launch(void* const* d_in, const int* in_sizes, int n_in,
                              void* d_out, int out_size, void* d_ws, size_t ws_size,
                              hipStream_t stream) {
    (void)in_sizes; (void)n_in; (void)out_size; (void)ws_size;
    const float* x    = (const float*)d_in[0];
    const float* ldt  = (const float*)d_in[1];
    const float* Arl  = (const float*)d_in[2];
    const float* Aim  = (const float*)d_in[3];
    const float* Bre  = (const float*)d_in[4];
    const float* Bim  = (const float*)d_in[5];
    const float* Cre  = (const float*)d_in[6];
    const float* Cim  = (const float*)d_in[7];
    const float* Dv   = (const float*)d_in[8];
    float* out = (float*)d_out;
    float* st_re = out + (size_t)B_ * L_ * H_;       // ys first
    float* st_im = st_re + (size_t)B_ * H_ * N2_;    // then imag plane

    // xT (H,B,L) f16 = 32 MiB lives in out's y region (y not written until
    // kernel C, which doesn't read xT). yT (32 MiB) lives in the workspace.
    f16* xT = (f16*)out;
    f16* yT = (f16*)d_ws;

    hipLaunchKernelGGL(k_trin, dim3(64 * 8 * B_), dim3(256), 0, stream, x, xT);
    hipLaunchKernelGGL(s4d_conv_kernel, dim3(1024), dim3(THREADS), 0, stream,
                       xT, ldt, Arl, Aim, Bre, Bim, Cre, Cim, Dv,
                       yT, st_re, st_im);
    hipLaunchKernelGGL(k_trout, dim3(64 * 8 * B_), dim3(256), 0, stream,
                       yT, out);
}

// Round 12
// 187.242 us; speedup vs baseline: 1.6050x; 1.0009x over previous
//
#include <hip/hip_runtime.h>
#include <math.h>

// S4D — round 18: r17 pipeline with VECTORIZED transposes.
//   A: x (B,L,H) f32 -> xT (H,B,L) f16. float4 loads (1KB/wave), f16x4
//      stores (512B/wave); LDS [64][65] pad -> all accesses 2-way (free).
//      VMEM instrs per thread: 32 -> 8 (the r17 transposes were
//      instruction-issue-bound: ~33M scalar VMEM ops each, ~50us).
//   B: conv kernel BYTE-IDENTICAL to r17 (verified, 54us).
//   C: yT (H,B,L) f16 -> y (B,L,H) f32, same vectorization.

#define H_  512
#define L_  4096
#define B_  8
#define N2_ 32
#define NC  64            // chunks of 64 timesteps
#define THREADS 256
#define COLS 256          // columns per conv block = 4 b x 64 c
#define RSTR 72           // padded LDS row stride, f16 units

typedef _Float16 f16;
typedef _Float16 f16x8 __attribute__((ext_vector_type(8)));
typedef _Float16 f16x4 __attribute__((ext_vector_type(4)));
typedef float    f32x4 __attribute__((ext_vector_type(4)));

__device__ __forceinline__ float bfly1(float v) {   // xor 1: quad_perm [1,0,3,2]
    return __int_as_float(__builtin_amdgcn_update_dpp(
        0, __float_as_int(v), 0xB1, 0xf, 0xf, true));
}

// ---------------- kernel A: x (B,L,H) f32 -> xT (H,B,L) f16 ----------------
// tile (b, t0:64, h0:64). LDS tl[h][t] stride 65 (2-way banks everywhere).
__global__ __launch_bounds__(256) void k_trin(
    const float* __restrict__ x, f16* __restrict__ xT)
{
    __shared__ float tl[64][65];
    const int bid = (int)blockIdx.x;
    const int tt = bid & 63, hh = (bid >> 6) & 7, b = bid >> 9;
    const int t0 = tt * 64, h0 = hh * 64;
    const int tid = threadIdx.x;

    const float* src = x + ((size_t)b * L_ + t0) * H_ + h0;
#pragma unroll
    for (int i = 0; i < 4; ++i) {
        const int e = i * 256 + tid;
        const int t = e >> 4, hq = e & 15;          // load 4 consecutive h
        const f32x4 v = *(const f32x4*)&src[(size_t)t * H_ + hq * 4];
#pragma unroll
        for (int j = 0; j < 4; ++j) tl[hq * 4 + j][t] = v[j];
    }
    __syncthreads();
#pragma unroll
    for (int i = 0; i < 4; ++i) {
        const int e = i * 256 + tid;
        const int hI = e >> 4, tq = e & 15;         // store 4 consecutive t
        f16x4 pk;
#pragma unroll
        for (int j = 0; j < 4; ++j) pk[j] = (f16)tl[hI][tq * 4 + j];
        *(f16x4*)&xT[((size_t)(h0 + hI) * B_ + b) * L_ + t0 + tq * 4] = pk;
    }
}

// ---------------- kernel C: yT (H,B,L) f16 -> y (B,L,H) f32 ----------------
// tile (b, t0:64, h0:64). LDS tl[t][h] stride 65.
__global__ __launch_bounds__(256) void k_trout(
    const f16* __restrict__ yT, float* __restrict__ y)
{
    __shared__ float tl[64][65];
    const int bid = (int)blockIdx.x;
    const int tt = bid & 63, hh = (bid >> 6) & 7, b = bid >> 9;
    const int t0 = tt * 64, h0 = hh * 64;
    const int tid = threadIdx.x;

#pragma unroll
    for (int i = 0; i < 4; ++i) {
        const int e = i * 256 + tid;
        const int hI = e >> 4, tq = e & 15;         // load 4 consecutive t
        const f16x4 v = *(const f16x4*)
            &yT[((size_t)(h0 + hI) * B_ + b) * L_ + t0 + tq * 4];
#pragma unroll
        for (int j = 0; j < 4; ++j) tl[tq * 4 + j][hI] = (float)v[j];
    }
    __syncthreads();
    float* dst = y + ((size_t)b * L_ + t0) * H_ + h0;
#pragma unroll
    for (int i = 0; i < 4; ++i) {
        const int e = i * 256 + tid;
        const int t = e >> 4, hq = e & 15;          // store 4 consecutive h
        f32x4 v;
#pragma unroll
        for (int j = 0; j < 4; ++j) v[j] = tl[t][hq * 4 + j];
        *(f32x4*)&dst[(size_t)t * H_ + hq * 4] = v;
    }
}

// ---------------- kernel B: per-h chunked convolution (r17, verified) -----
__global__ __launch_bounds__(THREADS, 2) void s4d_conv_kernel(
    const f16*  __restrict__ xT,          // (H, B, L) f16
    const float* __restrict__ log_dt,     // (H,)
    const float* __restrict__ A_real_log, // (H, N2)
    const float* __restrict__ A_imag,     // (H, N2)
    const float* __restrict__ B_re,       // (H, N2)
    const float* __restrict__ B_im,       // (H, N2)
    const float* __restrict__ C_re,       // (H, N2)
    const float* __restrict__ C_im,       // (H, N2)
    const float* __restrict__ Dv,         // (H,)
    f16*  __restrict__ yT,                // (H, B, L) f16 (gelu'd)
    float* __restrict__ st_re,            // (B, H, N2)
    float* __restrict__ st_im)            // (B, H, N2)
{
    __shared__ f16 Xl[COLS][RSTR];                 // 36.9 KB
    __shared__ f16 PU[COLS][RSTR];                 // 36.9 KB
    __shared__ float s_xr[32], s_xi[32], s_dBr[32], s_dBi[32],
                     s_wr[32], s_wi[32], s_wdr[32], s_wdi[32],
                     s_Lr[32], s_Li[32], s_k[64];

    // XCD swizzle: XCD k owns h in [k*64, (k+1)*64), both b-halves.
    const int bid = (int)blockIdx.x;
    const int li  = bid >> 3;                       // 0..127
    const int h   = (bid & 7) * 64 + (li >> 1);
    const int bh  = li & 1;                         // batch half (b = bh*4+w)

    const int tid = threadIdx.x;
    const int l   = tid & 63;
    const int w   = tid >> 6;                       // wave = local batch

    // ---- P0: per-mode ZOH constants (32 threads) ----
    if (tid < 32) {
        const int n = tid, hn = h * N2_ + n;
        const float dt = expf(log_dt[h]);
        const float Ar = -expf(A_real_log[hn]);
        const float Ai = A_imag[hn];
        const float xr = dt * Ar, xi = dt * Ai;
        s_xr[n] = xr; s_xi[n] = xi;
        const float ex = expf(xr), cs = cosf(xi), sn = sinf(xi);
        const float sh  = sinf(0.5f * xi);
        const float emr = expm1f(xr) * cs - 2.0f * sh * sh;  // Re(expm1(dtA))
        const float emi = ex * sn;
        const float ia  = 1.0f / (Ar * Ar + Ai * Ai);
        const float tr  = (emr * Ar + emi * Ai) * ia;
        const float ti  = (emi * Ar - emr * Ai) * ia;
        const float Brv = B_re[hn], Biv = B_im[hn];
        const float dBr = Brv * tr - Biv * ti, dBi = Brv * ti + Biv * tr;
        s_dBr[n] = dBr; s_dBi[n] = dBi;
        const float wr = 2.0f * C_re[hn], wi = 2.0f * C_im[hn];
        s_wr[n] = wr; s_wi[n] = wi;
        s_wdr[n] = wr * dBr - wi * dBi;             // w*dB
        s_wdi[n] = wr * dBi + wi * dBr;
    }
    const float Dh = Dv[h];
    __syncthreads();

    // ---- P1: dApow[p][n] = dA_n^p, p = 0..64, in PU area (f32) ----
    float* pr = (float*)&PU[0][0];                  // [65*32]
    float* pi = pr + 65 * 32;
    for (int e = tid; e < 65 * 32; e += THREADS) {
        const int p = e >> 5, n = e & 31;
        const float ex = expf((float)p * s_xr[n]);
        float sn, cs; sincosf((float)p * s_xi[n], &sn, &cs);
        pr[e] = ex * cs; pi[e] = ex * sn;
    }
    __syncthreads();

    // ---- P2: build k, Lambda, M, V (then T after barrier) ----
    if (tid < 64) {                                 // k[d] = Re(w dB dA^d)
        float acc = 0.f;
        for (int n = 0; n < 32; ++n)
            acc += s_wdr[n] * pr[tid * 32 + n] - s_wdi[n] * pi[tid * 32 + n];
        s_k[tid] = acc;
    }
    if (tid < 32) { s_Lr[tid] = pr[64 * 32 + tid]; s_Li[tid] = pi[64 * 32 + tid]; }
    for (int e = tid; e < 4096; e += THREADS) {     // M[t][j], rows 64..127
        const int t = e >> 6, j = e & 63, n = j >> 1;
        const float re = pr[(t + 1) * 32 + n], im = pi[(t + 1) * 32 + n];
        const float mv = (j & 1) ? -(s_wr[n] * im + s_wi[n] * re)
                                 :  (s_wr[n] * re - s_wi[n] * im);
        Xl[64 + t][j] = (f16)mv;
    }
    for (int e = tid; e < 4096; e += THREADS) {     // V[r][s], rows 128..191
        const int r = e >> 6, s = e & 63, n = r >> 1;
        const float re = pr[(63 - s) * 32 + n], im = pi[(63 - s) * 32 + n];
        const float vv = (r & 1) ? (s_dBr[n] * im + s_dBi[n] * re)
                                 : (s_dBr[n] * re - s_dBi[n] * im);
        Xl[128 + r][s] = (f16)vv;
    }
    __syncthreads();
    for (int e = tid; e < 4096; e += THREADS) {     // T[t][s], rows 0..63
        const int t = e >> 6, s = e & 63;
        Xl[t][s] = (f16)((s <= t) ? s_k[t - s] : 0.f);
    }
    __syncthreads();

    // ---- P3: A-fragments to registers (row = l&15, kgroup = l>>4) ----
    const int row16 = l & 15, kg = l >> 4;
    f16x8 Tf[4][2], Mf[4][2], Vf[4][2];
#pragma unroll
    for (int mt = 0; mt < 4; ++mt)
#pragma unroll
        for (int ks = 0; ks < 2; ++ks) {
            const int off = ks * 32 + kg * 8;
            Tf[mt][ks] = *(const f16x8*)&Xl[      mt * 16 + row16][off];
            Mf[mt][ks] = *(const f16x8*)&Xl[ 64 + mt * 16 + row16][off];
            Vf[mt][ks] = *(const f16x8*)&Xl[128 + mt * 16 + row16][off];
        }
    __syncthreads();   // frags live in regs; Xl area free for X

    // ---- P4: load X — CONTIGUOUS f16 reads from xT (thread = column) ----
    {
        const int col = tid, b = bh * 4 + (col >> 6), c = col & 63;
        const f16* xg = xT + ((size_t)h * B_ + b) * L_ + (size_t)c * 64;
#pragma unroll
        for (int s0 = 0; s0 < 64; s0 += 8)
            *(f16x8*)&Xl[col][s0] = *(const f16x8*)&xg[s0];
    }
    __syncthreads();

    const int colbase = w * 64;

    // ---- P5: P = V @ X for this wave's 64 columns ----
#pragma unroll 1
    for (int nt = 0; nt < 4; ++nt) {
        const int col = colbase + nt * 16 + row16;
        const f16x8 xb0 = *(const f16x8*)&Xl[col][kg * 8];
        const f16x8 xb1 = *(const f16x8*)&Xl[col][32 + kg * 8];
        f32x4 ac0 = {0.f,0.f,0.f,0.f}, ac1 = {0.f,0.f,0.f,0.f},
              ac2 = {0.f,0.f,0.f,0.f}, ac3 = {0.f,0.f,0.f,0.f};
        ac0 = __builtin_amdgcn_mfma_f32_16x16x32_f16(Vf[0][0], xb0, ac0, 0,0,0);
        ac0 = __builtin_amdgcn_mfma_f32_16x16x32_f16(Vf[0][1], xb1, ac0, 0,0,0);
        ac1 = __builtin_amdgcn_mfma_f32_16x16x32_f16(Vf[1][0], xb0, ac1, 0,0,0);
        ac1 = __builtin_amdgcn_mfma_f32_16x16x32_f16(Vf[1][1], xb1, ac1, 0,0,0);
        ac2 = __builtin_amdgcn_mfma_f32_16x16x32_f16(Vf[2][0], xb0, ac2, 0,0,0);
        ac2 = __builtin_amdgcn_mfma_f32_16x16x32_f16(Vf[2][1], xb1, ac2, 0,0,0);
        ac3 = __builtin_amdgcn_mfma_f32_16x16x32_f16(Vf[3][0], xb0, ac3, 0,0,0);
        ac3 = __builtin_amdgcn_mfma_f32_16x16x32_f16(Vf[3][1], xb1, ac3, 0,0,0);
        f32x4 a4[4] = {ac0, ac1, ac2, ac3};
#pragma unroll
        for (int mt = 0; mt < 4; ++mt) {
            f16x4 pv;
            pv[0] = (f16)a4[mt][0]; pv[1] = (f16)a4[mt][1];
            pv[2] = (f16)a4[mt][2]; pv[3] = (f16)a4[mt][3];
            *(f16x4*)&PU[col][mt * 16 + kg * 4] = pv;   // row j, col
        }
    }

    // ---- P6: wave-local diagonal recurrence over chunks (b = bh*4+w) ----
    {
        const int j = l, n = j >> 1;
        const float lr  = s_Lr[n];
        const float lis = (j & 1) ? s_Li[n] : -s_Li[n];
        float u = 0.f;
        for (int c = 0; c < NC; ++c) {
            const int col = colbase + c;
            const float pv = (float)PU[col][j];     // P_c component
            PU[col][j] = (f16)u;                    // store u_in(c) pre-update
            const float usw = bfly1(u);
            u = fmaf(lr, u, fmaf(lis, usw, pv));
        }
        const int pairIdx = (bh * 4 + w) * H_ + h;
        if ((j & 1) == 0) st_re[(size_t)pairIdx * N2_ + n] = u;
        else              st_im[(size_t)pairIdx * N2_ + n] = u;
    }

    // ---- P7: Y = T @ X + M @ U + D*x, gelu, CONTIGUOUS f16 store to yT ----
    {
        const int b = bh * 4 + w;
        f16* yb = yT + ((size_t)h * B_ + b) * L_;
#pragma unroll 1
        for (int nt = 0; nt < 4; ++nt) {
            const int col = colbase + nt * 16 + row16;
            const int cc  = nt * 16 + row16;        // chunk index
            const f16x8 xb0 = *(const f16x8*)&Xl[col][kg * 8];
            const f16x8 xb1 = *(const f16x8*)&Xl[col][32 + kg * 8];
            const f16x8 ub0 = *(const f16x8*)&PU[col][kg * 8];
            const f16x8 ub1 = *(const f16x8*)&PU[col][32 + kg * 8];
#pragma unroll
            for (int mt = 0; mt < 4; ++mt) {
                f32x4 ac = {0.f, 0.f, 0.f, 0.f};
                ac = __builtin_amdgcn_mfma_f32_16x16x32_f16(Tf[mt][0], xb0, ac, 0,0,0);
                ac = __builtin_amdgcn_mfma_f32_16x16x32_f16(Tf[mt][1], xb1, ac, 0,0,0);
                ac = __builtin_amdgcn_mfma_f32_16x16x32_f16(Mf[mt][0], ub0, ac, 0,0,0);
                ac = __builtin_amdgcn_mfma_f32_16x16x32_f16(Mf[mt][1], ub1, ac, 0,0,0);
                const int t0 = mt * 16 + kg * 4;
                const f16x4 xs = *(const f16x4*)&Xl[col][t0];
                f16x4 pk;
#pragma unroll
                for (int r = 0; r < 4; ++r) {
                    const float y  = fmaf(Dh, (float)xs[r], ac[r]);
                    const float y2 = y * y;
                    const float arg = y * fmaf(-0.10294502f, y2, -2.30218425f);
                    const float e   = __builtin_amdgcn_exp2f(arg);
                    pk[r] = (f16)(y * __builtin_amdgcn_rcpf(1.0f + e));
                }
                *(f16x4*)&yb[(size_t)cc * 64 + t0] = pk;
            }
        }
    }
}

extern "C" void kernel_launch(void* const* d_in, const int* in_sizes, int n_in,
                              void* d_out, int out_size, void* d_ws, size_t ws_size,
                              hipStream_t stream) {
    (void)in_sizes; (void)n_in; (void)out_size; (void)ws_size;
    const float* x    = (const float*)d_in[0];
    const float* ldt  = (const float*)d_in[1];
    const float* Arl  = (const float*)d_in[2];
    const float* Aim  = (const float*)d_in[3];
    const float* Bre  = (const float*)d_in[4];
    const float* Bim  = (const float*)d_in[5];
    const float* Cre  = (const float*)d_in[6];
    const float* Cim  = (const float*)d_in[7];
    const float* Dv   = (const float*)d_in[8];
    float* out = (float*)d_out;
    float* st_re = out + (size_t)B_ * L_ * H_;       // ys first
    float* st_im = st_re + (size_t)B_ * H_ * N2_;    // then imag plane

    // xT (H,B,L) f16 = 32 MiB lives in out's y region (y not written until
    // kernel C, which doesn't read xT). yT (32 MiB) lives in the workspace.
    f16* xT = (f16*)out;
    f16* yT = (f16*)d_ws;

    hipLaunchKernelGGL(k_trin, dim3(64 * 8 * B_), dim3(256), 0, stream, x, xT);
    hipLaunchKernelGGL(s4d_conv_kernel, dim3(1024), dim3(THREADS), 0, stream,
                       xT, ldt, Arl, Aim, Bre, Bim, Cre, Cim, Dv,
                       yT, st_re, st_im);
    hipLaunchKernelGGL(k_trout, dim3(64 * 8 * B_), dim3(256), 0, stream,
                       yT, out);
}